// Round 5
// baseline (43421.976 us; speedup 1.0000x reference)
//
#include <hip/hip_runtime.h>
#include <stdint.h>

#define T_STEPS 4096
#define HID     768
#define G3      2304      // 3*HID
#define NWORK   32        // worker blocks (elected onto ONE XCD)
#define NTHR    768       // 12 waves per worker block
#define UPB     24        // hidden units per worker block (32*24 = 768)
#define NLAUNCH 2048      // launched blocks; non-elected blocks exit at once
#define FAST_DEADLINE 4000   // bounded sc0 fast-poll iterations
#define FB_BOUND      50000  // bounded agent-scope fallback iterations

typedef unsigned int uint4v __attribute__((ext_vector_type(4)));

// ---------------- threefry2x32 (matches jax._src.prng exactly) ----------------
__device__ __forceinline__ void threefry2x32(uint32_t k0, uint32_t k1,
                                             uint32_t x0, uint32_t x1,
                                             uint32_t* o0, uint32_t* o1) {
  uint32_t ks[3] = {k0, k1, k0 ^ k1 ^ 0x1BD11BDAu};
  x0 += ks[0]; x1 += ks[1];
  const int r0[4] = {13, 15, 26, 6};
  const int r1[4] = {17, 29, 16, 24};
#pragma unroll
  for (int i = 0; i < 5; ++i) {
    const int* rr = (i & 1) ? r1 : r0;
#pragma unroll
    for (int j = 0; j < 4; ++j) {
      x0 += x1;
      x1 = (x1 << rr[j]) | (x1 >> (32 - rr[j]));
      x1 ^= x0;
    }
    x0 += ks[(i + 1) % 3];
    x1 += ks[(i + 2) % 3] + (uint32_t)(i + 1);
  }
  *o0 = x0; *o1 = x1;
}

__device__ __forceinline__ float gumbel_from_bits(uint32_t bits) {
  float f = __uint_as_float((bits >> 9) | 0x3f800000u) - 1.0f;
  float u = fmaxf(f, 1.17549435e-38f);
  return -logf(-logf(u));
}

// ---- init: pair buffer 0 = (h0, tag 0), buffer 1 = tag -1; reset ctrl ----------
__global__ void init_pairs(const float* __restrict__ h0,
                           unsigned long long* __restrict__ pairs,
                           int* __restrict__ ctrl) {
  int j = threadIdx.x;
  if (j < HID) {
    pairs[j]       = (unsigned long long)__float_as_uint(h0[j]);  // tag 0 high word
    pairs[HID + j] = 0xFFFFFFFF00000000ull;                       // tag -1
  }
  if (j == 0) { ctrl[0] = -1; ctrl[1] = 0; }                      // target xcc, claim
}

// ---------------- GEMM: xi = inputs(4096x768) @ Wi(768x2304) + bi  (fp32) ------
__launch_bounds__(256)
__global__ void gemm_xi(const float* __restrict__ A, const float* __restrict__ B,
                        const float* __restrict__ bias, float* __restrict__ C) {
  const int N = G3, K = HID;
  __shared__ __align__(16) float As[8][128];
  __shared__ __align__(16) float Bs[8][128];
  int tid = threadIdx.x;
  int bn = blockIdx.x * 128;
  int bm = blockIdx.y * 128;
  int tx = tid & 15, ty = tid >> 4;

  float acc[8][8];
#pragma unroll
  for (int i = 0; i < 8; ++i)
#pragma unroll
    for (int j = 0; j < 8; ++j) acc[i][j] = 0.f;

  const int ar = tid >> 1;
  const int ac = (tid & 1) * 4;
  const int br = tid >> 5;
  const int bc = (tid & 31) * 4;
  const float* Aptr = A + (size_t)(bm + ar) * K + ac;
  const float* Bptr = B + (size_t)br * N + bn + bc;

  for (int k0 = 0; k0 < K; k0 += 8) {
    float4 av = *(const float4*)(Aptr + k0);
    float4 bv = *(const float4*)(Bptr + (size_t)k0 * N);
    As[ac + 0][ar] = av.x; As[ac + 1][ar] = av.y;
    As[ac + 2][ar] = av.z; As[ac + 3][ar] = av.w;
    *(float4*)&Bs[br][bc] = bv;
    __syncthreads();
#pragma unroll
    for (int kk = 0; kk < 8; ++kk) {
      float a[8], b[8];
      *(float4*)&a[0] = *(const float4*)&As[kk][ty * 8];
      *(float4*)&a[4] = *(const float4*)&As[kk][ty * 8 + 4];
      *(float4*)&b[0] = *(const float4*)&Bs[kk][tx * 8];
      *(float4*)&b[4] = *(const float4*)&Bs[kk][tx * 8 + 4];
#pragma unroll
      for (int i = 0; i < 8; ++i)
#pragma unroll
        for (int j = 0; j < 8; ++j) acc[i][j] = fmaf(a[i], b[j], acc[i][j]);
    }
    __syncthreads();
  }
#pragma unroll
  for (int i = 0; i < 8; ++i) {
    float* crow = C + (size_t)(bm + ty * 8 + i) * N + bn + tx * 8;
    const float* brow = bias + bn + tx * 8;
#pragma unroll
    for (int j = 0; j < 8; ++j) crow[j] = acc[i][j] + brow[j];
  }
}

// ---- poll one (value,tag) pair until tag==want.
// Fast phase: sc0 load (XCD-L2, L1-bypass), bounded. On deadline miss, stickily
// degrade to agent-scope atomic load (proven correct in rounds 2/3: reads the
// device coherence point). Fallback also bounded -> kernel always terminates.
__device__ __forceinline__ unsigned long long poll_pair(
    const unsigned long long* __restrict__ p, unsigned int want, bool& use_fb) {
  unsigned long long v;
  if (!use_fb) {
    int it = 0;
    do {
      asm volatile("global_load_dwordx2 %0, %1, off sc0\n\t"
                   "s_waitcnt vmcnt(0)"
                   : "=&v"(v) : "v"(p) : "memory");
      if ((unsigned int)(v >> 32) == want) return v;
    } while (++it < FAST_DEADLINE);
    use_fb = true;   // sticky: never trust the fast path again on this thread
  }
  int it = 0;
  do {
    v = __hip_atomic_load(p, __ATOMIC_RELAXED, __HIP_MEMORY_SCOPE_AGENT);
    if ((unsigned int)(v >> 32) == want) return v;
  } while (++it < FB_BOUND);
  return v;  // give up: wrong-but-terminating beats a 600s harness wedge
}

// ---------------- persistent GRU scan, single-XCD with safe fallback -------------
// 32 worker blocks elected onto ONE XCD (HW_REG_XCC_ID + CAS + slot counter); all
// other blocks exit. Producers publish (h,tag) pairs with agent-scope atomic
// stores (device coherence point, proven) plus an sc0 store to seed the local
// XCD L2 for the fast poll path. Block = 12 waves; wave w owns units
// (24s+2w, 24s+2w+1); lane l holds Wh rows {64i+l} for both units' 3 columns.
__launch_bounds__(NTHR)
__global__ void gru_scan(const float* __restrict__ xi, const float* __restrict__ Wh,
                         const float* __restrict__ bhn, const float* __restrict__ h0,
                         unsigned long long* __restrict__ pairs,
                         int* __restrict__ ctrl, float* __restrict__ y) {
  __shared__ int s_slot;
  __shared__ float h_lds[2][HID];

  int xcc;
  asm volatile("s_getreg_b32 %0, hwreg(HW_REG_XCC_ID)" : "=s"(xcc));

  if (threadIdx.x == 0) {
    int slot = -1;
    int old = atomicCAS(&ctrl[0], -1, xcc);
    if (old == -1 || old == xcc)
      slot = (int)atomicAdd((unsigned int*)&ctrl[1], 1u);
    s_slot = slot;
  }
  __syncthreads();
  const int slot = s_slot;
  if (slot < 0 || slot >= NWORK) return;

  const int tid  = threadIdx.x;
  const int lane = tid & 63;
  const int w    = tid >> 6;              // wave 0..11
  const int uA   = slot * UPB + 2 * w;    // even unit
  const int uB   = uA + 1;

  // register-resident weights: rows 64i+lane of 6 columns (uA,uB) x (r,z,n)
  float wrA[12], wzA[12], wnA[12], wrB[12], wzB[12], wnB[12];
#pragma unroll
  for (int i = 0; i < 12; ++i) {
    const float* row = Wh + (size_t)(64 * i + lane) * G3;
    wrA[i] = row[uA];            wrB[i] = row[uB];
    wzA[i] = row[HID + uA];      wzB[i] = row[HID + uB];
    wnA[i] = row[2 * HID + uA];  wnB[i] = row[2 * HID + uB];
  }
  const float bhnA = bhn[uA], bhnB = bhn[uB];
  float hA = h0[uA], hB = h0[uB];         // tracked uniformly by all lanes
  bool use_fb = false;

  for (int t = 0; t < T_STEPS; ++t) {
    const int par = t & 1;

    // xi prefetch (wave-uniform addresses); completes under the poll latency
    const float* xrow = xi + (size_t)t * G3;
    float2 xr2 = *(const float2*)(xrow + uA);
    float2 xz2 = *(const float2*)(xrow + HID + uA);
    float2 xn2 = *(const float2*)(xrow + 2 * HID + uA);

    // poll own pair slot (thread j -> global pair j) until tag == t
    {
      unsigned long long v =
          poll_pair(pairs + (size_t)par * HID + tid, (unsigned int)t, use_fb);
      h_lds[par][tid] = __uint_as_float((unsigned int)v);
    }
    __syncthreads();

    // matvec: 12 rows x 6 columns from LDS (stride-64 reads: conflict-free)
    float ar0 = 0.f, az0 = 0.f, an0 = 0.f, ar1 = 0.f, az1 = 0.f, an1 = 0.f;
    const float* hb = h_lds[par];
#pragma unroll
    for (int i = 0; i < 12; ++i) {
      float hv = hb[64 * i + lane];
      ar0 = fmaf(hv, wrA[i], ar0);
      az0 = fmaf(hv, wzA[i], az0);
      an0 = fmaf(hv, wnA[i], an0);
      ar1 = fmaf(hv, wrB[i], ar1);
      az1 = fmaf(hv, wzB[i], az1);
      an1 = fmaf(hv, wnB[i], an1);
    }
#pragma unroll
    for (int m = 1; m < 64; m <<= 1) {
      ar0 += __shfl_xor(ar0, m, 64);
      az0 += __shfl_xor(az0, m, 64);
      an0 += __shfl_xor(an0, m, 64);
      ar1 += __shfl_xor(ar1, m, 64);
      az1 += __shfl_xor(az1, m, 64);
      an1 += __shfl_xor(an1, m, 64);
    }

    // gates: all lanes compute uniformly (no divergence); lane 0 publishes
    float rA = 1.f / (1.f + expf(-(xr2.x + ar0)));
    float zA = 1.f / (1.f + expf(-(xz2.x + az0)));
    float nA = tanhf(xn2.x + rA * (an0 + bhnA));
    hA = (1.f - zA) * nA + zA * hA;

    float rB = 1.f / (1.f + expf(-(xr2.y + ar1)));
    float zB = 1.f / (1.f + expf(-(xz2.y + az1)));
    float nB = tanhf(xn2.y + rB * (an1 + bhnB));
    hB = (1.f - zB) * nB + zB * hB;

    if (lane == 0) {
      *(float2*)(y + (size_t)t * HID + uA) = make_float2(hA, hB);
      unsigned long long pA =
          (((unsigned long long)(unsigned int)(t + 1)) << 32) | __float_as_uint(hA);
      unsigned long long pB =
          (((unsigned long long)(unsigned int)(t + 1)) << 32) | __float_as_uint(hB);
      unsigned long long* dst = pairs + (size_t)((t + 1) & 1) * HID + uA;
      // seed local XCD L2 for the fast poll path...
      uint4v pv;
      pv[0] = (unsigned int)pA; pv[1] = (unsigned int)(pA >> 32);
      pv[2] = (unsigned int)pB; pv[3] = (unsigned int)(pB >> 32);
      asm volatile("global_store_dwordx4 %0, %1, off sc0"
                   :: "v"(dst), "v"(pv) : "memory");
      // ...and publish at the device coherence point (proven path, fallback anchor)
      __hip_atomic_store(dst,     pA, __ATOMIC_RELAXED, __HIP_MEMORY_SCOPE_AGENT);
      __hip_atomic_store(dst + 1, pB, __ATOMIC_RELAXED, __HIP_MEMORY_SCOPE_AGENT);
    }
  }
}

// ---------------- decode: out = y@Wd + bd ; action = argmax(out[:, :2] + gumbel) ---
__launch_bounds__(256)
__global__ void decode_out(const float* __restrict__ y, const float* __restrict__ Wd,
                           const float* __restrict__ bd, float* __restrict__ out) {
  int tid = threadIdx.x;
  int lane = tid & 63;
  int wid = tid >> 6;
  int r = blockIdx.x * 4 + wid;
  const float* yr = y + (size_t)r * HID;

  float acc0 = 0.f, acc1 = 0.f, acc2 = 0.f, acc3 = 0.f;
#pragma unroll
  for (int i = 0; i < 12; ++i) {
    int k = lane + 64 * i;
    float yv = yr[k];
    float4 wd = *(const float4*)&Wd[(size_t)k * 4];
    acc0 = fmaf(yv, wd.x, acc0);
    acc1 = fmaf(yv, wd.y, acc1);
    acc2 = fmaf(yv, wd.z, acc2);
    acc3 = fmaf(yv, wd.w, acc3);
    if (r == T_STEPS - 1) out[20480 + k] = yv;   // final_h
  }
#pragma unroll
  for (int m = 32; m >= 1; m >>= 1) {
    acc0 += __shfl_xor(acc0, m, 64);
    acc1 += __shfl_xor(acc1, m, 64);
    acc2 += __shfl_xor(acc2, m, 64);
    acc3 += __shfl_xor(acc3, m, 64);
  }
  if (lane == 0) {
    float o0 = acc0 + bd[0], o1 = acc1 + bd[1], o2 = acc2 + bd[2], o3 = acc3 + bd[3];
    out[(size_t)r * 4 + 0] = o0;
    out[(size_t)r * 4 + 1] = o1;
    out[(size_t)r * 4 + 2] = o2;
    out[(size_t)r * 4 + 3] = o3;

    // jax PRNG, threefry_partitionable (verified round 2)
    uint32_t ak0, ak1;
    threefry2x32(0u, 42u, 0u, 1u, &ak0, &ak1);
    uint32_t s0, s1;
    threefry2x32(ak0, ak1, 0u, (uint32_t)(2 * r), &s0, &s1);
    uint32_t g0bits = s0 ^ s1;
    threefry2x32(ak0, ak1, 0u, (uint32_t)(2 * r + 1), &s0, &s1);
    uint32_t g1bits = s0 ^ s1;

    float gg0 = gumbel_from_bits(g0bits);
    float gg1 = gumbel_from_bits(g1bits);
    int action = (o1 + gg1 > o0 + gg0) ? 1 : 0;
    out[16384 + r] = (float)action;
  }
}

// ---------------- launch -----------------------------------------------------------
extern "C" void kernel_launch(void* const* d_in, const int* in_sizes, int n_in,
                              void* d_out, int out_size, void* d_ws, size_t ws_size,
                              hipStream_t stream) {
  const float* inputs = (const float*)d_in[0];
  const float* h0     = (const float*)d_in[1];
  const float* Wi     = (const float*)d_in[2];
  const float* bi     = (const float*)d_in[3];
  const float* Wh     = (const float*)d_in[4];
  const float* bhn    = (const float*)d_in[5];
  const float* Wd     = (const float*)d_in[6];
  const float* bd     = (const float*)d_in[7];
  float* out = (float*)d_out;

  char* ws = (char*)d_ws;
  unsigned long long* pairs = (unsigned long long*)ws;              // 2*768*8 = 12 KB
  int* ctrl = (int*)(ws + 12288);                                   // {target, claim}
  float* xi = (float*)(ws + 16384);                                 // 4096*2304*4
  float* y  = (float*)(ws + 16384 + (size_t)T_STEPS * G3 * 4);      // 4096*768*4

  hipLaunchKernelGGL(init_pairs, dim3(1), dim3(HID), 0, stream, h0, pairs, ctrl);
  hipLaunchKernelGGL(gemm_xi, dim3(G3 / 128, T_STEPS / 128), dim3(256), 0, stream,
                     inputs, Wi, bi, xi);
  hipLaunchKernelGGL(gru_scan, dim3(NLAUNCH), dim3(NTHR), 0, stream,
                     xi, Wh, bhn, h0, pairs, ctrl, y);
  hipLaunchKernelGGL(decode_out, dim3(T_STEPS / 4), dim3(256), 0, stream, y, Wd, bd, out);
}

// Round 6
// 11978.143 us; speedup vs baseline: 3.6251x; 3.6251x over previous
//
#include <hip/hip_runtime.h>
#include <stdint.h>

#define T_STEPS 4096
#define HID     768
#define G3      2304      // 3*HID
#define NBLK    192       // one wave per block, 4 units each
#define NTHR    64
#define UPB     4

// ---------------- threefry2x32 (matches jax._src.prng exactly) ----------------
__device__ __forceinline__ void threefry2x32(uint32_t k0, uint32_t k1,
                                             uint32_t x0, uint32_t x1,
                                             uint32_t* o0, uint32_t* o1) {
  uint32_t ks[3] = {k0, k1, k0 ^ k1 ^ 0x1BD11BDAu};
  x0 += ks[0]; x1 += ks[1];
  const int r0[4] = {13, 15, 26, 6};
  const int r1[4] = {17, 29, 16, 24};
#pragma unroll
  for (int i = 0; i < 5; ++i) {
    const int* rr = (i & 1) ? r1 : r0;
#pragma unroll
    for (int j = 0; j < 4; ++j) {
      x0 += x1;
      x1 = (x1 << rr[j]) | (x1 >> (32 - rr[j]));
      x1 ^= x0;
    }
    x0 += ks[(i + 1) % 3];
    x1 += ks[(i + 2) % 3] + (uint32_t)(i + 1);
  }
  *o0 = x0; *o1 = x1;
}

__device__ __forceinline__ float gumbel_from_bits(uint32_t bits) {
  float f = __uint_as_float((bits >> 9) | 0x3f800000u) - 1.0f;
  float u = fmaxf(f, 1.17549435e-38f);
  return -logf(-logf(u));
}

// ---- init: pair buffer 0 = (h0, tag 0), buffer 1 = tag -1 ----------------------
__global__ void init_pairs(const float* __restrict__ h0,
                           unsigned long long* __restrict__ pairs) {
  int j = threadIdx.x;
  if (j < HID) {
    pairs[j]       = (unsigned long long)__float_as_uint(h0[j]);  // tag 0 high word
    pairs[HID + j] = 0xFFFFFFFF00000000ull;                       // tag -1
  }
}

// ---------------- GEMM: xi = inputs(4096x768) @ Wi(768x2304) + bi  (fp32) ------
__launch_bounds__(256)
__global__ void gemm_xi(const float* __restrict__ A, const float* __restrict__ B,
                        const float* __restrict__ bias, float* __restrict__ C) {
  const int N = G3, K = HID;
  __shared__ __align__(16) float As[8][128];
  __shared__ __align__(16) float Bs[8][128];
  int tid = threadIdx.x;
  int bn = blockIdx.x * 128;
  int bm = blockIdx.y * 128;
  int tx = tid & 15, ty = tid >> 4;

  float acc[8][8];
#pragma unroll
  for (int i = 0; i < 8; ++i)
#pragma unroll
    for (int j = 0; j < 8; ++j) acc[i][j] = 0.f;

  const int ar = tid >> 1;
  const int ac = (tid & 1) * 4;
  const int br = tid >> 5;
  const int bc = (tid & 31) * 4;
  const float* Aptr = A + (size_t)(bm + ar) * K + ac;
  const float* Bptr = B + (size_t)br * N + bn + bc;

  for (int k0 = 0; k0 < K; k0 += 8) {
    float4 av = *(const float4*)(Aptr + k0);
    float4 bv = *(const float4*)(Bptr + (size_t)k0 * N);
    As[ac + 0][ar] = av.x; As[ac + 1][ar] = av.y;
    As[ac + 2][ar] = av.z; As[ac + 3][ar] = av.w;
    *(float4*)&Bs[br][bc] = bv;
    __syncthreads();
#pragma unroll
    for (int kk = 0; kk < 8; ++kk) {
      float a[8], b[8];
      *(float4*)&a[0] = *(const float4*)&As[kk][ty * 8];
      *(float4*)&a[4] = *(const float4*)&As[kk][ty * 8 + 4];
      *(float4*)&b[0] = *(const float4*)&Bs[kk][tx * 8];
      *(float4*)&b[4] = *(const float4*)&Bs[kk][tx * 8 + 4];
#pragma unroll
      for (int i = 0; i < 8; ++i)
#pragma unroll
        for (int j = 0; j < 8; ++j) acc[i][j] = fmaf(a[i], b[j], acc[i][j]);
    }
    __syncthreads();
  }
#pragma unroll
  for (int i = 0; i < 8; ++i) {
    float* crow = C + (size_t)(bm + ty * 8 + i) * N + bn + tx * 8;
    const float* brow = bias + bn + tx * 8;
#pragma unroll
    for (int j = 0; j < 8; ++j) crow[j] = acc[i][j] + brow[j];
  }
}

// ---------------- persistent GRU scan: 1 wave / 4 units, no LDS, no barriers -----
// Block b (one wave) owns units u0..u0+3 (u0=4b). Lane l polls pairs {64i+l}
// (wave sweep = 12 coalesced 512B loads) with a got-mask so steady-state reloads
// only stragglers. Lane l also holds Wh rows {64i+l} for the block's 12 columns
// (d = gate*4+unit) in 144 VGPRs; dots accumulate directly from polled registers.
// One 72-shfl butterfly gives every lane all 12 dots; lanes 0..3 compute gates
// and publish (value,tag) pairs with relaxed AGENT atomic stores (r2-proven).
// Race-freedom: a wave stores tag t+1 only after its full poll of tag t, so a
// parity slot is never overwritten before every wave consumed the previous tag.
__launch_bounds__(NTHR, 1)
__global__ void gru_scan(const float* __restrict__ xi, const float* __restrict__ Wh,
                         const float* __restrict__ bhn, const float* __restrict__ h0,
                         unsigned long long* __restrict__ pairs,
                         float* __restrict__ y) {
  const int lane = threadIdx.x;
  const int u0   = blockIdx.x * UPB;

  // weights: w[d][i] = Wh[64i+lane][col(d)], col(d) = (d>>2)*HID + u0 + (d&3)
  float w[12][12];
#pragma unroll
  for (int i = 0; i < 12; ++i) {
    const float* row = Wh + (size_t)(64 * i + lane) * G3;
#pragma unroll
    for (int d = 0; d < 12; ++d)
      w[d][i] = row[(d >> 2) * HID + u0 + (d & 3)];
  }

  // lane j<4 owns unit u0+j: its bias, running h, and xi row slots
  float bhn_u = 0.f, h_cur = 0.f;
  if (lane < UPB) {
    bhn_u = bhn[u0 + lane];
    h_cur = h0[u0 + lane];
  }

  for (int t = 0; t < T_STEPS; ++t) {
    const unsigned long long* buf = pairs + (size_t)(t & 1) * HID;

    // xi prefetch for lanes 0..3 (issued before the poll; completes under it)
    float xr = 0.f, xz = 0.f, xn = 0.f;
    if (lane < UPB) {
      const float* xrow = xi + (size_t)t * G3 + u0 + lane;
      xr = xrow[0];
      xz = xrow[HID];
      xn = xrow[2 * HID];
    }

    // poll the 12 owned pairs; early-exit per pair via got-mask
    float hval[12];
    unsigned int got = 0;
    while (got != 0xFFFu) {
      unsigned long long v[12];
#pragma unroll
      for (int i = 0; i < 12; ++i)
        if (!(got & (1u << i)))
          v[i] = __hip_atomic_load(&buf[64 * i + lane], __ATOMIC_RELAXED,
                                   __HIP_MEMORY_SCOPE_AGENT);
#pragma unroll
      for (int i = 0; i < 12; ++i)
        if (!(got & (1u << i)) &&
            (unsigned int)(v[i] >> 32) == (unsigned int)t) {
          hval[i] = __uint_as_float((unsigned int)v[i]);
          got |= (1u << i);
        }
    }

    // 144 FMA: 12 h-chunks x 12 columns, independent chains per column
    float acc[12];
#pragma unroll
    for (int d = 0; d < 12; ++d) acc[d] = 0.f;
#pragma unroll
    for (int i = 0; i < 12; ++i) {
      float hv = hval[i];
#pragma unroll
      for (int d = 0; d < 12; ++d) acc[d] = fmaf(hv, w[d][i], acc[d]);
    }
    // butterfly: every lane ends with all 12 full dots
#pragma unroll
    for (int m = 1; m < 64; m <<= 1) {
#pragma unroll
      for (int d = 0; d < 12; ++d) acc[d] += __shfl_xor(acc[d], m, 64);
    }

    // lanes 0..3: gates + publish
    if (lane < UPB) {
      float r = 1.f / (1.f + expf(-(xr + acc[lane])));
      float z = 1.f / (1.f + expf(-(xz + acc[4 + lane])));
      float n = tanhf(xn + r * (acc[8 + lane] + bhn_u));
      h_cur = (1.f - z) * n + z * h_cur;
      y[(size_t)t * HID + u0 + lane] = h_cur;
      unsigned long long pv =
          (((unsigned long long)(unsigned int)(t + 1)) << 32) | __float_as_uint(h_cur);
      __hip_atomic_store(&pairs[(size_t)((t + 1) & 1) * HID + u0 + lane], pv,
                         __ATOMIC_RELAXED, __HIP_MEMORY_SCOPE_AGENT);
    }
  }
}

// ---------------- decode: out = y@Wd + bd ; action = argmax(out[:, :2] + gumbel) ---
__launch_bounds__(256)
__global__ void decode_out(const float* __restrict__ y, const float* __restrict__ Wd,
                           const float* __restrict__ bd, float* __restrict__ out) {
  int tid = threadIdx.x;
  int lane = tid & 63;
  int wid = tid >> 6;
  int r = blockIdx.x * 4 + wid;
  const float* yr = y + (size_t)r * HID;

  float acc0 = 0.f, acc1 = 0.f, acc2 = 0.f, acc3 = 0.f;
#pragma unroll
  for (int i = 0; i < 12; ++i) {
    int k = lane + 64 * i;
    float yv = yr[k];
    float4 wd = *(const float4*)&Wd[(size_t)k * 4];
    acc0 = fmaf(yv, wd.x, acc0);
    acc1 = fmaf(yv, wd.y, acc1);
    acc2 = fmaf(yv, wd.z, acc2);
    acc3 = fmaf(yv, wd.w, acc3);
    if (r == T_STEPS - 1) out[20480 + k] = yv;   // final_h
  }
#pragma unroll
  for (int m = 32; m >= 1; m >>= 1) {
    acc0 += __shfl_xor(acc0, m, 64);
    acc1 += __shfl_xor(acc1, m, 64);
    acc2 += __shfl_xor(acc2, m, 64);
    acc3 += __shfl_xor(acc3, m, 64);
  }
  if (lane == 0) {
    float o0 = acc0 + bd[0], o1 = acc1 + bd[1], o2 = acc2 + bd[2], o3 = acc3 + bd[3];
    out[(size_t)r * 4 + 0] = o0;
    out[(size_t)r * 4 + 1] = o1;
    out[(size_t)r * 4 + 2] = o2;
    out[(size_t)r * 4 + 3] = o3;

    // jax PRNG, threefry_partitionable (verified round 2)
    uint32_t ak0, ak1;
    threefry2x32(0u, 42u, 0u, 1u, &ak0, &ak1);
    uint32_t s0, s1;
    threefry2x32(ak0, ak1, 0u, (uint32_t)(2 * r), &s0, &s1);
    uint32_t g0bits = s0 ^ s1;
    threefry2x32(ak0, ak1, 0u, (uint32_t)(2 * r + 1), &s0, &s1);
    uint32_t g1bits = s0 ^ s1;

    float gg0 = gumbel_from_bits(g0bits);
    float gg1 = gumbel_from_bits(g1bits);
    int action = (o1 + gg1 > o0 + gg0) ? 1 : 0;
    out[16384 + r] = (float)action;
  }
}

// ---------------- launch -----------------------------------------------------------
extern "C" void kernel_launch(void* const* d_in, const int* in_sizes, int n_in,
                              void* d_out, int out_size, void* d_ws, size_t ws_size,
                              hipStream_t stream) {
  const float* inputs = (const float*)d_in[0];
  const float* h0     = (const float*)d_in[1];
  const float* Wi     = (const float*)d_in[2];
  const float* bi     = (const float*)d_in[3];
  const float* Wh     = (const float*)d_in[4];
  const float* bhn    = (const float*)d_in[5];
  const float* Wd     = (const float*)d_in[6];
  const float* bd     = (const float*)d_in[7];
  float* out = (float*)d_out;

  char* ws = (char*)d_ws;
  unsigned long long* pairs = (unsigned long long*)ws;              // 2*768*8 = 12 KB
  float* xi = (float*)(ws + 16384);                                 // 4096*2304*4
  float* y  = (float*)(ws + 16384 + (size_t)T_STEPS * G3 * 4);      // 4096*768*4

  hipLaunchKernelGGL(init_pairs, dim3(1), dim3(HID), 0, stream, h0, pairs);
  hipLaunchKernelGGL(gemm_xi, dim3(G3 / 128, T_STEPS / 128), dim3(256), 0, stream,
                     inputs, Wi, bi, xi);

  {
    const float* xi_c = xi;
    const float* wh_c = Wh;
    const float* bhn_c = bhn;
    const float* h0_c = h0;
    unsigned long long* pr = pairs;
    float* y_p = y;
    void* args[] = { (void*)&xi_c, (void*)&wh_c, (void*)&bhn_c, (void*)&h0_c,
                     (void*)&pr, (void*)&y_p };
    hipError_t e = hipLaunchCooperativeKernel((const void*)gru_scan, dim3(NBLK),
                                              dim3(NTHR), args, 0, stream);
    if (e != hipSuccess) {
      hipLaunchKernelGGL(gru_scan, dim3(NBLK), dim3(NTHR), 0, stream,
                         xi_c, wh_c, bhn_c, h0_c, pr, y_p);
    }
  }

  hipLaunchKernelGGL(decode_out, dim3(T_STEPS / 4), dim3(256), 0, stream, y, Wd, bd, out);
}